// Round 1
// baseline (1223.474 us; speedup 1.0000x reference)
//
#include <hip/hip_runtime.h>
#include <hip/hip_bf16.h>

#define E_ 8
#define H_ 4096
#define I_ 1792
#define TWOI_ 3584
#define T_ 4096
#define NSLOT_ 8192

typedef __attribute__((ext_vector_type(4))) float f32x4;
typedef __attribute__((ext_vector_type(8))) short bf16x8;

static __device__ __forceinline__ short f2bf(float f) {
    unsigned u = __builtin_bit_cast(unsigned, f);
    u += 0x7FFF + ((u >> 16) & 1);   // round-to-nearest-even
    return (short)(u >> 16);
}

// ---------------- routing: build per-expert token lists ----------------
__global__ void route_kernel(const int* __restrict__ eidx,
                             const float* __restrict__ aff,
                             int* __restrict__ cnt, int* __restrict__ off,
                             int* __restrict__ toks, float* __restrict__ wts) {
    __shared__ int scnt[E_];
    __shared__ int soff[E_];
    int tid = threadIdx.x;
    if (tid < E_) scnt[tid] = 0;
    __syncthreads();
    for (int s = tid; s < NSLOT_; s += blockDim.x) {
        atomicAdd(&scnt[eidx[s]], 1);
    }
    __syncthreads();
    if (tid == 0) {
        int acc = 0;
        for (int e = 0; e < E_; ++e) {
            int c = scnt[e];
            cnt[e] = c; off[e] = acc; soff[e] = acc;
            acc += c;
        }
    }
    __syncthreads();
    if (tid < E_) scnt[tid] = soff[tid];   // reuse as cursors
    __syncthreads();
    for (int s = tid; s < NSLOT_; s += blockDim.x) {
        int t = s >> 1;
        int e0 = eidx[t * 2], e1 = eidx[t * 2 + 1];
        float a0 = aff[t * E_ + e0], a1 = aff[t * E_ + e1];
        int k = s & 1;
        int e = k ? e1 : e0;
        float w = (k ? a1 : a0) / (a0 + a1);   // normalize_top_k_affinities
        int pos = atomicAdd(&scnt[e], 1);
        toks[pos] = t;
        wts[pos] = w;
    }
}

// ---------------- GEMM1: x @ Wgu -> silu(gate)*up, bf16 h ----------------
// block: 128 slots x (64 gate cols + 64 up cols), BK=32, 4 waves (2x2)
__global__ __launch_bounds__(256) void gemm1_kernel(
    const float* __restrict__ x,        // [T,H]
    const int* __restrict__ wq,         // [E,H,2I] uint8 codes in int32
    const float* __restrict__ scale,    // [E,2I]
    const int* __restrict__ cnt, const int* __restrict__ off,
    const int* __restrict__ toks,
    short* __restrict__ h_ws) {         // [NSLOT,I] bf16
    int e = blockIdx.z;
    int cn = cnt[e];
    int row0 = blockIdx.y * 128;
    if (row0 >= cn) return;
    int base = off[e];
    int c0 = blockIdx.x * 64;

    __shared__ __align__(16) short As[4][128][8];   // k-packet layout
    __shared__ __align__(16) short Bg[4][64][8];
    __shared__ __align__(16) short Bu[4][64][8];
    __shared__ int stok[128];

    int tid = threadIdx.x;
    if (tid < 128) {
        int r = row0 + tid;
        stok[tid] = toks[base + (r < cn ? r : 0)];
    }
    __syncthreads();

    const int lane = tid & 63;
    const int wid = tid >> 6;
    const int wr = (wid >> 1) * 64;
    const int wc = (wid & 1) * 32;
    const int fr = lane & 15;
    const int kg = lane >> 4;

    f32x4 accg[4][2], accu[4][2];
    #pragma unroll
    for (int i = 0; i < 4; ++i)
        #pragma unroll
        for (int j = 0; j < 2; ++j) {
            accg[i][j] = f32x4{0.f, 0.f, 0.f, 0.f};
            accu[i][j] = f32x4{0.f, 0.f, 0.f, 0.f};
        }

    const int ar = tid & 127;            // A staging row
    const int akg = (tid >> 7) * 2;      // A staging kg start (2 packets)
    const int bc = tid & 63;             // B staging col
    const int bkg = (tid >> 6) & 3;      // B staging kg

    const float* xrow = x + (size_t)stok[ar] * H_;
    const int* wg = wq + (size_t)e * H_ * TWOI_ + c0 + bc;
    const int* wu = wg + I_;

    for (int kk = 0; kk < H_; kk += 32) {
        // ---- stage A (gathered tokens, f32 -> bf16) ----
        {
            const float* xp = xrow + kk + akg * 8;
            #pragma unroll
            for (int p = 0; p < 2; ++p) {
                float4 f0 = *(const float4*)(xp + p * 8);
                float4 f1 = *(const float4*)(xp + p * 8 + 4);
                bf16x8 v;
                v[0] = f2bf(f0.x); v[1] = f2bf(f0.y); v[2] = f2bf(f0.z); v[3] = f2bf(f0.w);
                v[4] = f2bf(f1.x); v[5] = f2bf(f1.y); v[6] = f2bf(f1.z); v[7] = f2bf(f1.w);
                *(bf16x8*)&As[akg + p][ar][0] = v;
            }
        }
        // ---- stage B (fused dequant, (q-128) exact in bf16) ----
        {
            const int* wpg = wg + (size_t)(kk + bkg * 8) * TWOI_;
            const int* wpu = wu + (size_t)(kk + bkg * 8) * TWOI_;
            bf16x8 vg, vu;
            #pragma unroll
            for (int j = 0; j < 8; ++j) {
                vg[j] = f2bf((float)wpg[(size_t)j * TWOI_] - 128.f);
                vu[j] = f2bf((float)wpu[(size_t)j * TWOI_] - 128.f);
            }
            *(bf16x8*)&Bg[bkg][bc][0] = vg;
            *(bf16x8*)&Bu[bkg][bc][0] = vu;
        }
        __syncthreads();
        bf16x8 a[4], bg[2], bu[2];
        #pragma unroll
        for (int rf = 0; rf < 4; ++rf) a[rf] = *(const bf16x8*)&As[kg][wr + rf * 16 + fr][0];
        #pragma unroll
        for (int cf = 0; cf < 2; ++cf) {
            bg[cf] = *(const bf16x8*)&Bg[kg][wc + cf * 16 + fr][0];
            bu[cf] = *(const bf16x8*)&Bu[kg][wc + cf * 16 + fr][0];
        }
        #pragma unroll
        for (int rf = 0; rf < 4; ++rf)
            #pragma unroll
            for (int cf = 0; cf < 2; ++cf) {
                accg[rf][cf] = __builtin_amdgcn_mfma_f32_16x16x32_bf16(a[rf], bg[cf], accg[rf][cf], 0, 0, 0);
                accu[rf][cf] = __builtin_amdgcn_mfma_f32_16x16x32_bf16(a[rf], bu[cf], accu[rf][cf], 0, 0, 0);
            }
        __syncthreads();
    }

    // ---- epilogue: scales + silu(g)*u -> bf16 h ----
    const int q4 = lane >> 4;
    #pragma unroll
    for (int cf = 0; cf < 2; ++cf) {
        int col = c0 + wc + cf * 16 + fr;
        float gs = scale[e * TWOI_ + col];
        float us = scale[e * TWOI_ + I_ + col];
        #pragma unroll
        for (int rf = 0; rf < 4; ++rf) {
            #pragma unroll
            for (int j = 0; j < 4; ++j) {
                int row = wr + rf * 16 + q4 * 4 + j;
                if (row0 + row < cn) {
                    float g = accg[rf][cf][j] * gs;
                    float u = accu[rf][cf][j] * us;
                    float s = 1.f / (1.f + __expf(-g));
                    h_ws[(size_t)(base + row0 + row) * I_ + col] = f2bf(g * s * u);
                }
            }
        }
    }
}

// ---------------- GEMM2: h @ Wd -> scaled, combine-weighted atomicAdd ----------------
// block: 128 slots x 128 H cols, BK=32, 4 waves (2x2)
__global__ __launch_bounds__(256) void gemm2_kernel(
    const short* __restrict__ h_ws,     // [NSLOT,I] bf16
    const int* __restrict__ wq,         // [E,I,H]
    const float* __restrict__ dscale,   // [E,H]
    const int* __restrict__ cnt, const int* __restrict__ off,
    const int* __restrict__ toks, const float* __restrict__ wts,
    float* __restrict__ out) {          // [T,H]
    int e = blockIdx.z;
    int cn = cnt[e];
    int row0 = blockIdx.y * 128;
    if (row0 >= cn) return;
    int base = off[e];
    int c0 = blockIdx.x * 128;

    __shared__ __align__(16) short As[4][128][8];
    __shared__ __align__(16) short Bs[4][128][8];
    __shared__ int stok[128];
    __shared__ float swt[128];

    int tid = threadIdx.x;
    if (tid < 128) {
        int r = row0 + tid;
        int idx = base + (r < cn ? r : 0);
        stok[tid] = toks[idx];
        swt[tid] = (r < cn) ? wts[idx] : 0.f;
    }
    __syncthreads();

    const int lane = tid & 63;
    const int wid = tid >> 6;
    const int wr = (wid >> 1) * 64;
    const int wc = (wid & 1) * 64;
    const int fr = lane & 15;
    const int kg = lane >> 4;

    f32x4 acc[4][4];
    #pragma unroll
    for (int i = 0; i < 4; ++i)
        #pragma unroll
        for (int j = 0; j < 4; ++j) acc[i][j] = f32x4{0.f, 0.f, 0.f, 0.f};

    const int ar = tid & 127;
    const int akg = (tid >> 7) * 2;
    const int bc = tid & 127;
    const int bkg2 = (tid >> 7) * 2;

    const short* hrow = h_ws + (size_t)(base + ((row0 + ar) < cn ? row0 + ar : 0)) * I_;
    const int* wcol = wq + (size_t)e * I_ * H_ + c0 + bc;

    for (int kk = 0; kk < I_; kk += 32) {
        #pragma unroll
        for (int p = 0; p < 2; ++p) {
            *(bf16x8*)&As[akg + p][ar][0] = *(const bf16x8*)(hrow + kk + (akg + p) * 8);
        }
        #pragma unroll
        for (int p = 0; p < 2; ++p) {
            const int* wp = wcol + (size_t)(kk + (bkg2 + p) * 8) * H_;
            bf16x8 v;
            #pragma unroll
            for (int j = 0; j < 8; ++j) v[j] = f2bf((float)wp[(size_t)j * H_] - 128.f);
            *(bf16x8*)&Bs[bkg2 + p][bc][0] = v;
        }
        __syncthreads();
        bf16x8 a[4], b[4];
        #pragma unroll
        for (int rf = 0; rf < 4; ++rf) a[rf] = *(const bf16x8*)&As[kg][wr + rf * 16 + fr][0];
        #pragma unroll
        for (int cf = 0; cf < 4; ++cf) b[cf] = *(const bf16x8*)&Bs[kg][wc + cf * 16 + fr][0];
        #pragma unroll
        for (int rf = 0; rf < 4; ++rf)
            #pragma unroll
            for (int cf = 0; cf < 4; ++cf)
                acc[rf][cf] = __builtin_amdgcn_mfma_f32_16x16x32_bf16(a[rf], b[cf], acc[rf][cf], 0, 0, 0);
        __syncthreads();
    }

    const int q4 = lane >> 4;
    #pragma unroll
    for (int cf = 0; cf < 4; ++cf) {
        int col = c0 + wc + cf * 16 + fr;
        float ds = dscale[e * H_ + col];
        #pragma unroll
        for (int rf = 0; rf < 4; ++rf) {
            #pragma unroll
            for (int j = 0; j < 4; ++j) {
                int row = wr + rf * 16 + q4 * 4 + j;
                if (row0 + row < cn) {
                    float v = acc[rf][cf][j] * ds * swt[row];
                    atomicAdd(&out[(size_t)stok[row] * H_ + col], v);
                }
            }
        }
    }
}

extern "C" void kernel_launch(void* const* d_in, const int* in_sizes, int n_in,
                              void* d_out, int out_size, void* d_ws, size_t ws_size,
                              hipStream_t stream) {
    const float* x     = (const float*)d_in[0];   // hidden_states [T,H]
    const float* aff   = (const float*)d_in[1];   // expert_affinities [T,E]
    const int*   guq   = (const int*)d_in[2];     // gate_up_w_q [E,H,2I]
    const float* gus   = (const float*)d_in[3];   // gate_up_scale [E,1,2I]
    const int*   dwq   = (const int*)d_in[4];     // down_w_q [E,I,H]
    const float* dsc   = (const float*)d_in[5];   // down_scale [E,1,H]
    const int*   eidx  = (const int*)d_in[6];     // expert_index [T,K]
    float* out = (float*)d_out;

    char* ws = (char*)d_ws;
    int* cnt = (int*)ws;                       // 8 ints
    int* off = cnt + 8;                        // 8 ints
    int* toks = (int*)(ws + 64);               // 8192 ints
    float* wts = (float*)(ws + 64 + NSLOT_ * 4);
    short* h_ws = (short*)(ws + (1 << 20));    // [8192,1792] bf16 = 29.4 MB

    hipMemsetAsync(d_out, 0, (size_t)out_size * sizeof(float), stream);
    route_kernel<<<1, 1024, 0, stream>>>(eidx, aff, cnt, off, toks, wts);

    dim3 g1(I_ / 64, NSLOT_ / 128, E_);
    gemm1_kernel<<<g1, 256, 0, stream>>>(x, guq, gus, cnt, off, toks, h_ws);

    dim3 g2(H_ / 128, NSLOT_ / 128, E_);
    gemm2_kernel<<<g2, 256, 0, stream>>>(h_ws, dwq, dsc, cnt, off, toks, wts, out);
}

// Round 2
// 975.144 us; speedup vs baseline: 1.2547x; 1.2547x over previous
//
#include <hip/hip_runtime.h>
#include <hip/hip_bf16.h>
#include <stdint.h>

#define E_ 8
#define H_ 4096
#define I_ 1792
#define TWOI_ 3584
#define T_ 4096
#define NSLOT_ 8192
#define KT1_ 128   /* H_/32 */
#define KT2_ 56    /* I_/32 */

typedef __attribute__((ext_vector_type(4))) float f32x4;
typedef __attribute__((ext_vector_type(8))) short bf16x8;

static __device__ __forceinline__ short f2bf(float f) {
    unsigned u = __builtin_bit_cast(unsigned, f);
    u += 0x7FFF + ((u >> 16) & 1);   // round-to-nearest-even
    return (short)(u >> 16);
}

static __device__ __forceinline__ void gld16(const void* g, void* l) {
    __builtin_amdgcn_global_load_lds(
        (const __attribute__((address_space(1))) void*)g,
        (__attribute__((address_space(3))) void*)l, 16, 0, 0);
}

// ---------------- routing: build per-expert token lists ----------------
__global__ void route_kernel(const int* __restrict__ eidx,
                             const float* __restrict__ aff,
                             int* __restrict__ cnt, int* __restrict__ off,
                             int* __restrict__ toks, float* __restrict__ wts) {
    __shared__ int scnt[E_];
    __shared__ int soff[E_];
    int tid = threadIdx.x;
    if (tid < E_) scnt[tid] = 0;
    __syncthreads();
    for (int s = tid; s < NSLOT_; s += blockDim.x) {
        atomicAdd(&scnt[eidx[s]], 1);
    }
    __syncthreads();
    if (tid == 0) {
        int acc = 0;
        for (int e = 0; e < E_; ++e) {
            int c = scnt[e];
            cnt[e] = c; off[e] = acc; soff[e] = acc;
            acc += c;
        }
    }
    __syncthreads();
    if (tid < E_) scnt[tid] = soff[tid];
    __syncthreads();
    for (int s = tid; s < NSLOT_; s += blockDim.x) {
        int t = s >> 1;
        int e0 = eidx[t * 2], e1 = eidx[t * 2 + 1];
        float a0 = aff[t * E_ + e0], a1 = aff[t * E_ + e1];
        int k = s & 1;
        int e = k ? e1 : e0;
        float w = (k ? a1 : a0) / (a0 + a1);
        int pos = atomicAdd(&scnt[e], 1);
        toks[pos] = t;
        wts[pos] = w;
    }
}

// ---------------- x f32 -> bf16 ----------------
__global__ __launch_bounds__(256) void xconv_kernel(const float* __restrict__ x,
                                                    short* __restrict__ xb) {
    size_t i = ((size_t)blockIdx.x * 256 + threadIdx.x) * 8;
    float4 f0 = *(const float4*)(x + i);
    float4 f1 = *(const float4*)(x + i + 4);
    bf16x8 v;
    v[0] = f2bf(f0.x); v[1] = f2bf(f0.y); v[2] = f2bf(f0.z); v[3] = f2bf(f0.w);
    v[4] = f2bf(f1.x); v[5] = f2bf(f1.y); v[6] = f2bf(f1.z); v[7] = f2bf(f1.w);
    *(bf16x8*)(xb + i) = v;
}

// ---------------- weight repack: int32 codes -> bf16 (q-128), MFMA tile order ----------------
// out[e][by=kt*4+kg][col][j] = (float)(w[e][by*8+j][col]) - 128, bf16
__global__ __launch_bounds__(256) void repack_gu_kernel(const int* __restrict__ wq,
                                                        short* __restrict__ out) {
    int e = blockIdx.z;
    int by = blockIdx.y;                           // 0..511
    int col = blockIdx.x * 256 + threadIdx.x;      // 0..3583
    const int* src = wq + ((size_t)e * H_ + by * 8) * TWOI_ + col;
    bf16x8 v;
    #pragma unroll
    for (int j = 0; j < 8; ++j)
        v[j] = f2bf((float)(src[(size_t)j * TWOI_] - 128));
    *(bf16x8*)(out + (((size_t)e * 512 + by) * TWOI_ + col) * 8) = v;
}

__global__ __launch_bounds__(256) void repack_dn_kernel(const int* __restrict__ wq,
                                                        short* __restrict__ out) {
    int e = blockIdx.z;
    int by = blockIdx.y;                           // 0..223
    int col = blockIdx.x * 256 + threadIdx.x;      // 0..4095
    const int* src = wq + ((size_t)e * I_ + by * 8) * H_ + col;
    bf16x8 v;
    #pragma unroll
    for (int j = 0; j < 8; ++j)
        v[j] = f2bf((float)(src[(size_t)j * H_] - 128));
    *(bf16x8*)(out + (((size_t)e * 224 + by) * H_ + col) * 8) = v;
}

// ---------------- GEMM1 fast: bf16 x @ bf16 Wgu -> silu(g)*u -> bf16 h ----------------
__global__ __launch_bounds__(256) void gemm1f_kernel(
    const short* __restrict__ xb,       // [T,H] bf16
    const short* __restrict__ wgu,      // repacked [E][512][3584][8] bf16
    const float* __restrict__ scale,    // [E,2I]
    const int* __restrict__ cnt, const int* __restrict__ off,
    const int* __restrict__ toks,
    short* __restrict__ h_ws) {         // [NSLOT,I] bf16
    int e = blockIdx.z;
    int cn = cnt[e];
    int row0 = blockIdx.y * 128;
    if (row0 >= cn) return;
    int base = off[e];
    int c0 = blockIdx.x * 64;

    __shared__ __align__(16) short As[4][128][8];
    __shared__ __align__(16) short Bs[4][128][8];   // cols 0-63 gate, 64-127 up
    __shared__ int stok[128];

    int tid = threadIdx.x;
    if (tid < 128) {
        int r = row0 + tid;
        stok[tid] = toks[base + (r < cn ? r : cn - 1)];
    }
    __syncthreads();

    const int lane = tid & 63;
    const int wid = tid >> 6;
    const int wrow = (wid >> 1) * 64;
    const int wc = (wid & 1) * 32;
    const int fr = lane & 15;
    const int kg = lane >> 4;

    // staging coords
    const int arow = tid & 127;
    const int kg0 = (tid >> 7) * 2;
    const int bkg = tid >> 6;
    const int bcol = tid & 63;

    const short* asrc = xb + (size_t)stok[arow] * H_;
    const short* bsrcg = wgu + (((size_t)e * 512 + bkg) * TWOI_ + c0 + bcol) * 8;
    short* dA0 = &As[kg0][arow][0];
    short* dA1 = &As[kg0 + 1][arow][0];
    short* dBg = &Bs[bkg][bcol][0];
    short* dBu = &Bs[bkg][64 + bcol][0];

    f32x4 accg[4][2], accu[4][2];
    #pragma unroll
    for (int i = 0; i < 4; ++i)
        #pragma unroll
        for (int j = 0; j < 2; ++j) {
            accg[i][j] = f32x4{0.f, 0.f, 0.f, 0.f};
            accu[i][j] = f32x4{0.f, 0.f, 0.f, 0.f};
        }

    for (int kt = 0; kt < KT1_; ++kt) {
        const int kk = kt * 32;
        gld16(asrc + kk + kg0 * 8, dA0);
        gld16(asrc + kk + (kg0 + 1) * 8, dA1);
        const short* bg = bsrcg + (size_t)kt * (4 * TWOI_ * 8);
        gld16(bg, dBg);
        gld16(bg + (size_t)I_ * 8, dBu);
        __syncthreads();
        bf16x8 a[4], g[2], u[2];
        #pragma unroll
        for (int rf = 0; rf < 4; ++rf) a[rf] = *(const bf16x8*)&As[kg][wrow + rf * 16 + fr][0];
        #pragma unroll
        for (int cf = 0; cf < 2; ++cf) {
            g[cf] = *(const bf16x8*)&Bs[kg][wc + cf * 16 + fr][0];
            u[cf] = *(const bf16x8*)&Bs[kg][64 + wc + cf * 16 + fr][0];
        }
        #pragma unroll
        for (int rf = 0; rf < 4; ++rf)
            #pragma unroll
            for (int cf = 0; cf < 2; ++cf) {
                accg[rf][cf] = __builtin_amdgcn_mfma_f32_16x16x32_bf16(a[rf], g[cf], accg[rf][cf], 0, 0, 0);
                accu[rf][cf] = __builtin_amdgcn_mfma_f32_16x16x32_bf16(a[rf], u[cf], accu[rf][cf], 0, 0, 0);
            }
        __syncthreads();
    }

    const int q4 = lane >> 4;
    #pragma unroll
    for (int cf = 0; cf < 2; ++cf) {
        int col = c0 + wc + cf * 16 + fr;
        float gs = scale[e * TWOI_ + col];
        float us = scale[e * TWOI_ + I_ + col];
        #pragma unroll
        for (int rf = 0; rf < 4; ++rf) {
            #pragma unroll
            for (int j = 0; j < 4; ++j) {
                int row = wrow + rf * 16 + q4 * 4 + j;
                if (row0 + row < cn) {
                    float gv = accg[rf][cf][j] * gs;
                    float uv = accu[rf][cf][j] * us;
                    float s = 1.f / (1.f + __expf(-gv));
                    h_ws[(size_t)(base + row0 + row) * I_ + col] = f2bf(gv * s * uv);
                }
            }
        }
    }
}

// ---------------- GEMM2 fast: bf16 h @ bf16 Wd -> combine-weighted atomicAdd ----------------
__global__ __launch_bounds__(256) void gemm2f_kernel(
    const short* __restrict__ h_ws,     // [NSLOT,I] bf16
    const short* __restrict__ wd,       // repacked [E][224][4096][8] bf16
    const float* __restrict__ dscale,   // [E,H]
    const int* __restrict__ cnt, const int* __restrict__ off,
    const int* __restrict__ toks, const float* __restrict__ wts,
    float* __restrict__ out) {          // [T,H]
    int e = blockIdx.z;
    int cn = cnt[e];
    int row0 = blockIdx.y * 128;
    if (row0 >= cn) return;
    int base = off[e];
    int c0 = blockIdx.x * 128;

    __shared__ __align__(16) short As[4][128][8];
    __shared__ __align__(16) short Bs[4][128][8];
    __shared__ int stok[128];
    __shared__ float swt[128];

    int tid = threadIdx.x;
    if (tid < 128) {
        int r = row0 + tid;
        int idx = base + (r < cn ? r : cn - 1);
        stok[tid] = toks[idx];
        swt[tid] = (r < cn) ? wts[idx] : 0.f;
    }
    __syncthreads();

    const int lane = tid & 63;
    const int wid = tid >> 6;
    const int wrow = (wid >> 1) * 64;
    const int wc = (wid & 1) * 64;
    const int fr = lane & 15;
    const int kg = lane >> 4;

    const int arow = tid & 127;
    const int kg0 = (tid >> 7) * 2;
    const int bkg = tid >> 6;
    const int bcol = tid & 63;

    int ar = row0 + arow;
    if (ar >= cn) ar = cn - 1;
    const short* asrc = h_ws + (size_t)(base + ar) * I_;
    const short* bsrc = wd + (((size_t)e * 224 + bkg) * H_ + c0 + bcol) * 8;
    short* dA0 = &As[kg0][arow][0];
    short* dA1 = &As[kg0 + 1][arow][0];
    short* dB0 = &Bs[bkg][bcol][0];
    short* dB1 = &Bs[bkg][64 + bcol][0];

    f32x4 acc[4][4];
    #pragma unroll
    for (int i = 0; i < 4; ++i)
        #pragma unroll
        for (int j = 0; j < 4; ++j) acc[i][j] = f32x4{0.f, 0.f, 0.f, 0.f};

    for (int kt = 0; kt < KT2_; ++kt) {
        const int kk = kt * 32;
        gld16(asrc + kk + kg0 * 8, dA0);
        gld16(asrc + kk + (kg0 + 1) * 8, dA1);
        const short* bp = bsrc + (size_t)kt * (4 * H_ * 8);
        gld16(bp, dB0);
        gld16(bp + 64 * 8, dB1);
        __syncthreads();
        bf16x8 a[4], b[4];
        #pragma unroll
        for (int rf = 0; rf < 4; ++rf) a[rf] = *(const bf16x8*)&As[kg][wrow + rf * 16 + fr][0];
        #pragma unroll
        for (int cf = 0; cf < 4; ++cf) b[cf] = *(const bf16x8*)&Bs[kg][wc + cf * 16 + fr][0];
        #pragma unroll
        for (int rf = 0; rf < 4; ++rf)
            #pragma unroll
            for (int cf = 0; cf < 4; ++cf)
                acc[rf][cf] = __builtin_amdgcn_mfma_f32_16x16x32_bf16(a[rf], b[cf], acc[rf][cf], 0, 0, 0);
        __syncthreads();
    }

    const int q4 = lane >> 4;
    #pragma unroll
    for (int cf = 0; cf < 4; ++cf) {
        int col = c0 + wc + cf * 16 + fr;
        float ds = dscale[e * H_ + col];
        #pragma unroll
        for (int rf = 0; rf < 4; ++rf) {
            #pragma unroll
            for (int j = 0; j < 4; ++j) {
                int row = wrow + rf * 16 + q4 * 4 + j;
                if (row0 + row < cn) {
                    float v = acc[rf][cf][j] * ds * swt[row];
                    atomicAdd(&out[(size_t)stok[row] * H_ + col], v);
                }
            }
        }
    }
}

// ================= fallback path (fused int32 dequant, known-good) =================
__global__ __launch_bounds__(256) void gemm1_kernel(
    const float* __restrict__ x, const int* __restrict__ wq,
    const float* __restrict__ scale,
    const int* __restrict__ cnt, const int* __restrict__ off,
    const int* __restrict__ toks, short* __restrict__ h_ws) {
    int e = blockIdx.z;
    int cn = cnt[e];
    int row0 = blockIdx.y * 128;
    if (row0 >= cn) return;
    int base = off[e];
    int c0 = blockIdx.x * 64;
    __shared__ __align__(16) short As[4][128][8];
    __shared__ __align__(16) short Bg[4][64][8];
    __shared__ __align__(16) short Bu[4][64][8];
    __shared__ int stok[128];
    int tid = threadIdx.x;
    if (tid < 128) {
        int r = row0 + tid;
        stok[tid] = toks[base + (r < cn ? r : 0)];
    }
    __syncthreads();
    const int lane = tid & 63;
    const int wid = tid >> 6;
    const int wrow = (wid >> 1) * 64;
    const int wc = (wid & 1) * 32;
    const int fr = lane & 15;
    const int kg = lane >> 4;
    f32x4 accg[4][2], accu[4][2];
    #pragma unroll
    for (int i = 0; i < 4; ++i)
        #pragma unroll
        for (int j = 0; j < 2; ++j) {
            accg[i][j] = f32x4{0.f, 0.f, 0.f, 0.f};
            accu[i][j] = f32x4{0.f, 0.f, 0.f, 0.f};
        }
    const int ar = tid & 127;
    const int akg = (tid >> 7) * 2;
    const int bc = tid & 63;
    const int bkg = (tid >> 6) & 3;
    const float* xrow = x + (size_t)stok[ar] * H_;
    const int* wg = wq + (size_t)e * H_ * TWOI_ + c0 + bc;
    const int* wu = wg + I_;
    for (int kk = 0; kk < H_; kk += 32) {
        {
            const float* xp = xrow + kk + akg * 8;
            #pragma unroll
            for (int p = 0; p < 2; ++p) {
                float4 f0 = *(const float4*)(xp + p * 8);
                float4 f1 = *(const float4*)(xp + p * 8 + 4);
                bf16x8 v;
                v[0] = f2bf(f0.x); v[1] = f2bf(f0.y); v[2] = f2bf(f0.z); v[3] = f2bf(f0.w);
                v[4] = f2bf(f1.x); v[5] = f2bf(f1.y); v[6] = f2bf(f1.z); v[7] = f2bf(f1.w);
                *(bf16x8*)&As[akg + p][ar][0] = v;
            }
        }
        {
            const int* wpg = wg + (size_t)(kk + bkg * 8) * TWOI_;
            const int* wpu = wu + (size_t)(kk + bkg * 8) * TWOI_;
            bf16x8 vg, vu;
            #pragma unroll
            for (int j = 0; j < 8; ++j) {
                vg[j] = f2bf((float)wpg[(size_t)j * TWOI_] - 128.f);
                vu[j] = f2bf((float)wpu[(size_t)j * TWOI_] - 128.f);
            }
            *(bf16x8*)&Bg[bkg][bc][0] = vg;
            *(bf16x8*)&Bu[bkg][bc][0] = vu;
        }
        __syncthreads();
        bf16x8 a[4], bg[2], bu[2];
        #pragma unroll
        for (int rf = 0; rf < 4; ++rf) a[rf] = *(const bf16x8*)&As[kg][wrow + rf * 16 + fr][0];
        #pragma unroll
        for (int cf = 0; cf < 2; ++cf) {
            bg[cf] = *(const bf16x8*)&Bg[kg][wc + cf * 16 + fr][0];
            bu[cf] = *(const bf16x8*)&Bu[kg][wc + cf * 16 + fr][0];
        }
        #pragma unroll
        for (int rf = 0; rf < 4; ++rf)
            #pragma unroll
            for (int cf = 0; cf < 2; ++cf) {
                accg[rf][cf] = __builtin_amdgcn_mfma_f32_16x16x32_bf16(a[rf], bg[cf], accg[rf][cf], 0, 0, 0);
                accu[rf][cf] = __builtin_amdgcn_mfma_f32_16x16x32_bf16(a[rf], bu[cf], accu[rf][cf], 0, 0, 0);
            }
        __syncthreads();
    }
    const int q4 = lane >> 4;
    #pragma unroll
    for (int cf = 0; cf < 2; ++cf) {
        int col = c0 + wc + cf * 16 + fr;
        float gs = scale[e * TWOI_ + col];
        float us = scale[e * TWOI_ + I_ + col];
        #pragma unroll
        for (int rf = 0; rf < 4; ++rf) {
            #pragma unroll
            for (int j = 0; j < 4; ++j) {
                int row = wrow + rf * 16 + q4 * 4 + j;
                if (row0 + row < cn) {
                    float gv = accg[rf][cf][j] * gs;
                    float uv = accu[rf][cf][j] * us;
                    float s = 1.f / (1.f + __expf(-gv));
                    h_ws[(size_t)(base + row0 + row) * I_ + col] = f2bf(gv * s * uv);
                }
            }
        }
    }
}

__global__ __launch_bounds__(256) void gemm2_kernel(
    const short* __restrict__ h_ws, const int* __restrict__ wq,
    const float* __restrict__ dscale,
    const int* __restrict__ cnt, const int* __restrict__ off,
    const int* __restrict__ toks, const float* __restrict__ wts,
    float* __restrict__ out) {
    int e = blockIdx.z;
    int cn = cnt[e];
    int row0 = blockIdx.y * 128;
    if (row0 >= cn) return;
    int base = off[e];
    int c0 = blockIdx.x * 128;
    __shared__ __align__(16) short As[4][128][8];
    __shared__ __align__(16) short Bs[4][128][8];
    __shared__ int stok[128];
    __shared__ float swt[128];
    int tid = threadIdx.x;
    if (tid < 128) {
        int r = row0 + tid;
        int idx = base + (r < cn ? r : 0);
        stok[tid] = toks[idx];
        swt[tid] = (r < cn) ? wts[idx] : 0.f;
    }
    __syncthreads();
    const int lane = tid & 63;
    const int wid = tid >> 6;
    const int wrow = (wid >> 1) * 64;
    const int wc = (wid & 1) * 64;
    const int fr = lane & 15;
    const int kg = lane >> 4;
    f32x4 acc[4][4];
    #pragma unroll
    for (int i = 0; i < 4; ++i)
        #pragma unroll
        for (int j = 0; j < 4; ++j) acc[i][j] = f32x4{0.f, 0.f, 0.f, 0.f};
    const int ar = tid & 127;
    const int akg = (tid >> 7) * 2;
    const int bc = tid & 127;
    const int bkg2 = (tid >> 7) * 2;
    const short* hrow = h_ws + (size_t)(base + ((row0 + ar) < cn ? row0 + ar : 0)) * I_;
    const int* wcol = wq + (size_t)e * I_ * H_ + c0 + bc;
    for (int kk = 0; kk < I_; kk += 32) {
        #pragma unroll
        for (int p = 0; p < 2; ++p) {
            *(bf16x8*)&As[akg + p][ar][0] = *(const bf16x8*)(hrow + kk + (akg + p) * 8);
        }
        #pragma unroll
        for (int p = 0; p < 2; ++p) {
            const int* wp = wcol + (size_t)(kk + (bkg2 + p) * 8) * H_;
            bf16x8 v;
            #pragma unroll
            for (int j = 0; j < 8; ++j) v[j] = f2bf((float)wp[(size_t)j * H_] - 128.f);
            *(bf16x8*)&Bs[bkg2 + p][bc][0] = v;
        }
        __syncthreads();
        bf16x8 a[4], b[4];
        #pragma unroll
        for (int rf = 0; rf < 4; ++rf) a[rf] = *(const bf16x8*)&As[kg][wrow + rf * 16 + fr][0];
        #pragma unroll
        for (int cf = 0; cf < 4; ++cf) b[cf] = *(const bf16x8*)&Bs[kg][wc + cf * 16 + fr][0];
        #pragma unroll
        for (int rf = 0; rf < 4; ++rf)
            #pragma unroll
            for (int cf = 0; cf < 4; ++cf)
                acc[rf][cf] = __builtin_amdgcn_mfma_f32_16x16x32_bf16(a[rf], b[cf], acc[rf][cf], 0, 0, 0);
        __syncthreads();
    }
    const int q4 = lane >> 4;
    #pragma unroll
    for (int cf = 0; cf < 4; ++cf) {
        int col = c0 + wc + cf * 16 + fr;
        float ds = dscale[e * H_ + col];
        #pragma unroll
        for (int rf = 0; rf < 4; ++rf) {
            #pragma unroll
            for (int j = 0; j < 4; ++j) {
                int row = wrow + rf * 16 + q4 * 4 + j;
                if (row0 + row < cn) {
                    float v = acc[rf][cf][j] * ds * swt[row];
                    atomicAdd(&out[(size_t)stok[row] * H_ + col], v);
                }
            }
        }
    }
}

extern "C" void kernel_launch(void* const* d_in, const int* in_sizes, int n_in,
                              void* d_out, int out_size, void* d_ws, size_t ws_size,
                              hipStream_t stream) {
    const float* x     = (const float*)d_in[0];
    const float* aff   = (const float*)d_in[1];
    const int*   guq   = (const int*)d_in[2];
    const float* gus   = (const float*)d_in[3];
    const int*   dwq   = (const int*)d_in[4];
    const float* dsc   = (const float*)d_in[5];
    const int*   eidx  = (const int*)d_in[6];
    float* out = (float*)d_out;

    char* ws = (char*)d_ws;
    int* cnt = (int*)ws;
    int* off = cnt + 8;
    int* toks = (int*)(ws + 64);
    float* wts = (float*)(ws + 64 + NSLOT_ * 4);

    const size_t off_h  = (size_t)1 << 20;
    const size_t sz_h   = (size_t)NSLOT_ * I_ * 2;          // 29,360,128
    const size_t off_xb = off_h + sz_h;
    const size_t sz_xb  = (size_t)T_ * H_ * 2;              // 33,554,432
    const size_t off_gu = off_xb + sz_xb;
    const size_t sz_gu  = (size_t)E_ * 512 * TWOI_ * 8 * 2; // 234,881,024
    const size_t off_dn = off_gu + sz_gu;
    const size_t sz_dn  = (size_t)E_ * 224 * H_ * 8 * 2;    // 117,440,512
    const size_t NEED   = off_dn + sz_dn;                   // ~416 MB

    short* h_ws = (short*)(ws + off_h);

    hipMemsetAsync(d_out, 0, (size_t)out_size * sizeof(float), stream);
    route_kernel<<<1, 1024, 0, stream>>>(eidx, aff, cnt, off, toks, wts);

    if (ws_size >= NEED) {
        short* xb   = (short*)(ws + off_xb);
        short* wgur = (short*)(ws + off_gu);
        short* wdr  = (short*)(ws + off_dn);

        xconv_kernel<<<(T_ * H_) / (256 * 8), 256, 0, stream>>>(x, xb);
        dim3 rg1(TWOI_ / 256, 512, E_);
        repack_gu_kernel<<<rg1, 256, 0, stream>>>(guq, wgur);
        dim3 rg2(H_ / 256, 224, E_);
        repack_dn_kernel<<<rg2, 256, 0, stream>>>(dwq, wdr);

        dim3 g1(I_ / 64, NSLOT_ / 128, E_);
        gemm1f_kernel<<<g1, 256, 0, stream>>>(xb, wgur, gus, cnt, off, toks, h_ws);
        dim3 g2(H_ / 128, NSLOT_ / 128, E_);
        gemm2f_kernel<<<g2, 256, 0, stream>>>(h_ws, wdr, dsc, cnt, off, toks, wts, out);
    } else {
        dim3 g1(I_ / 64, NSLOT_ / 128, E_);
        gemm1_kernel<<<g1, 256, 0, stream>>>(x, guq, gus, cnt, off, toks, h_ws);
        dim3 g2(H_ / 128, NSLOT_ / 128, E_);
        gemm2_kernel<<<g2, 256, 0, stream>>>(h_ws, dwq, dsc, cnt, off, toks, wts, out);
    }
}